// Round 1
// baseline (851.424 us; speedup 1.0000x reference)
//
#include <hip/hip_runtime.h>
#include <stdint.h>

// Problem constants
#define CCH   64
#define HWSZ  3136        // 56*56
#define NB    128
#define MCOLS 401408      // NB*HWSZ
#define TK    128         // K1 tile columns
#define LDK   136         // TK+8 bf16 stride (272 B, 16B-aligned, conflict-benign)
#define LDB   72          // K2 bf16 row stride (144 B, 16B-aligned)

typedef short bf16x8 __attribute__((ext_vector_type(8)));
typedef float f32x4  __attribute__((ext_vector_type(4)));

__device__ __forceinline__ unsigned short f2bf(float f) {
    union { float f; uint32_t u; } v; v.f = f;
    uint32_t r = v.u + 0x7fffu + ((v.u >> 16) & 1u);   // round-to-nearest-even
    return (unsigned short)(r >> 16);
}
__device__ __forceinline__ float bf2f(unsigned short h) {
    union { uint32_t u; float f; } v; v.u = ((uint32_t)h) << 16; return v.f;
}

// ---------------------------------------------------------------------------
// K1: per-channel sums + gram = X*X^T via bf16 MFMA (gram is symmetric =>
// immune to any C/D layout transpose). Partial results atomicAdd'ed to ws.
// ---------------------------------------------------------------------------
__global__ __launch_bounds__(256) void k1_gram(const float* __restrict__ X,
                                               float* __restrict__ gram,
                                               float* __restrict__ sums) {
    __shared__ __align__(16) unsigned short tile[CCH * LDK];  // 17408 B
    const int tid = threadIdx.x;
    const int w = tid >> 6, l = tid & 63;

    f32x4 acc[4];
    #pragma unroll
    for (int b = 0; b < 4; ++b) acc[b] = (f32x4){0.f, 0.f, 0.f, 0.f};
    float sacc[16];
    #pragma unroll
    for (int i = 0; i < 16; ++i) sacc[i] = 0.f;

    for (int it = 0; it < 2; ++it) {
        const uint32_t t0 = blockIdx.x * 2u + (uint32_t)it;
        const uint32_t s = t0 * TK + 2u * (uint32_t)l;  // column pair start
        const uint32_t n = s / HWSZ;
        const uint32_t hw = s - n * HWSZ;
        const size_t base = (size_t)n * (CCH * HWSZ) + hw + (size_t)w * HWSZ;

        __syncthreads();  // protect LDS from previous tile's readers
        // stage: channel c = 4*i + w, columns s..s+1 (float2, never crosses n)
        #pragma unroll
        for (int i = 0; i < 16; ++i) {
            const float2 xv = *(const float2*)(X + base + (size_t)i * (4u * HWSZ));
            sacc[i] += xv.x + xv.y;
            const int c = 4 * i + w;
            *(uint32_t*)&tile[c * LDK + 2 * l] =
                (uint32_t)f2bf(xv.x) | ((uint32_t)f2bf(xv.y) << 16);
        }
        __syncthreads();

        // MFMA: wave w computes gram blocks (row-block w, col-blocks 0..3)
        #pragma unroll
        for (int k0 = 0; k0 < TK; k0 += 32) {
            const int koff = k0 + ((l >> 4) << 3);
            const bf16x8 fa = *(const bf16x8*)&tile[(16 * w + (l & 15)) * LDK + koff];
            #pragma unroll
            for (int bj = 0; bj < 4; ++bj) {
                const bf16x8 fb = *(const bf16x8*)&tile[(16 * bj + (l & 15)) * LDK + koff];
                acc[bj] = __builtin_amdgcn_mfma_f32_16x16x32_bf16(fa, fb, acc[bj], 0, 0, 0);
            }
        }
    }

    // epilogue: atomics (once per block)
    #pragma unroll
    for (int bj = 0; bj < 4; ++bj) {
        #pragma unroll
        for (int r = 0; r < 4; ++r) {
            const int row = 16 * w + ((l >> 4) << 2) + r;
            const int col = 16 * bj + (l & 15);
            atomicAdd(&gram[row * 64 + col], acc[bj][r]);
        }
    }
    #pragma unroll
    for (int i = 0; i < 16; ++i) {
        float v = sacc[i];
        #pragma unroll
        for (int m = 32; m > 0; m >>= 1) v += __shfl_xor(v, m, 64);
        if (l == 0) atomicAdd(&sums[4 * i + w], v);
    }
}

// ---------------------------------------------------------------------------
// K2 helpers: 64x64 matmuls on one workgroup via MFMA. All operands are
// symmetric (polynomials in A), so B-frags read R's rows directly.
// ---------------------------------------------------------------------------
__device__ __forceinline__ bf16x8 ldfrag_h(const unsigned short* H, int rowbase, int k0, int l) {
    const int row = rowbase + (l & 15);
    const int koff = k0 + ((l >> 4) << 3);
    return *(const bf16x8*)&H[row * LDB + koff];
}
__device__ __forceinline__ bf16x8 ldfrag_lo(const float* F, bf16x8 hi, int rowbase, int k0, int l) {
    const int row = rowbase + (l & 15);
    const int koff = k0 + ((l >> 4) << 3);
    const float* p = F + row * 64 + koff;
    bf16x8 lo;
    #pragma unroll
    for (int j = 0; j < 8; ++j)
        lo[j] = (short)f2bf(p[j] - bf2f((unsigned short)hi[j]));
    return lo;
}

__device__ void mm_plain(const unsigned short* Lh, const unsigned short* Rh,
                         unsigned short* DH, float* DF, int tid) {
    const int w = tid >> 6, l = tid & 63;
    f32x4 acc[4];
    #pragma unroll
    for (int b = 0; b < 4; ++b) acc[b] = (f32x4){0.f, 0.f, 0.f, 0.f};
    #pragma unroll
    for (int k0 = 0; k0 < 64; k0 += 32) {
        const bf16x8 la = ldfrag_h(Lh, 16 * w, k0, l);
        #pragma unroll
        for (int b = 0; b < 4; ++b) {
            const bf16x8 rb = ldfrag_h(Rh, 16 * b, k0, l);
            acc[b] = __builtin_amdgcn_mfma_f32_16x16x32_bf16(la, rb, acc[b], 0, 0, 0);
        }
    }
    __syncthreads();  // allow in-place D==R
    #pragma unroll
    for (int b = 0; b < 4; ++b) {
        #pragma unroll
        for (int r = 0; r < 4; ++r) {
            const int row = 16 * w + ((l >> 4) << 2) + r;
            const int col = 16 * b + (l & 15);
            const float v = acc[b][r];
            if (DH) DH[row * LDB + col] = f2bf(v);
            if (DF) DF[row * 64 + col] = v;
        }
    }
    __syncthreads();
}

__device__ void mm_split(const unsigned short* Lh, const float* Lf,
                         const unsigned short* Rh, const float* Rf,
                         unsigned short* DH, float* DF, int tid) {
    const int w = tid >> 6, l = tid & 63;
    f32x4 acc[4];
    #pragma unroll
    for (int b = 0; b < 4; ++b) acc[b] = (f32x4){0.f, 0.f, 0.f, 0.f};
    #pragma unroll
    for (int k0 = 0; k0 < 64; k0 += 32) {
        const bf16x8 lah = ldfrag_h(Lh, 16 * w, k0, l);
        const bf16x8 lal = ldfrag_lo(Lf, lah, 16 * w, k0, l);
        #pragma unroll
        for (int b = 0; b < 4; ++b) {
            const bf16x8 rbh = ldfrag_h(Rh, 16 * b, k0, l);
            const bf16x8 rbl = ldfrag_lo(Rf, rbh, 16 * b, k0, l);
            acc[b] = __builtin_amdgcn_mfma_f32_16x16x32_bf16(lah, rbh, acc[b], 0, 0, 0);
            acc[b] = __builtin_amdgcn_mfma_f32_16x16x32_bf16(lah, rbl, acc[b], 0, 0, 0);
            acc[b] = __builtin_amdgcn_mfma_f32_16x16x32_bf16(lal, rbh, acc[b], 0, 0, 0);
        }
    }
    __syncthreads();  // allow in-place D==R
    #pragma unroll
    for (int b = 0; b < 4; ++b) {
        #pragma unroll
        for (int r = 0; r < 4; ++r) {
            const int row = 16 * w + ((l >> 4) << 2) + r;
            const int col = 16 * b + (l & 15);
            const float v = acc[b][r];
            if (DH) DH[row * LDB + col] = f2bf(v);
            if (DF) DF[row * 64 + col] = v;
        }
    }
    __syncthreads();
}

// ---------------------------------------------------------------------------
// K2: sigma -> Newton-Schulz inverse sqrt -> wm, b. Single workgroup.
// ---------------------------------------------------------------------------
__global__ __launch_bounds__(256) void k2_ns(float* __restrict__ ws) {
    const float* gram = ws;
    const float* sums = ws + 4096;
    float* wm = ws + 4160;
    float* bvec = ws + 8256;
    float* Ag = ws + 8320;  // fp32 A = sigma/s (global, for polish lo-frags)

    __shared__ float Zf[4096];
    __shared__ float Sf[4096];
    __shared__ __align__(16) unsigned short Ah[64 * LDB];
    __shared__ __align__(16) unsigned short ZhA[64 * LDB];
    __shared__ __align__(16) unsigned short Bh[64 * LDB];
    __shared__ float mu[64];
    __shared__ float sred[1];

    const int tid = threadIdx.x;
    const float invm = 1.0f / (float)MCOLS;

    if (tid < 64) mu[tid] = sums[tid] * invm;
    __syncthreads();

    // sigma -> Sf
    #pragma unroll
    for (int j = 0; j < 16; ++j) {
        const int e = tid * 16 + j;
        const int i = e >> 6, c = e & 63;
        Sf[e] = gram[e] * invm - mu[i] * mu[c] + ((i == c) ? 1e-3f : 0.0f);
    }
    __syncthreads();

    // s = ||sigma||_inf (Gershgorin bound on lambda_max)
    if (tid < 64) {
        float rs = 0.f;
        #pragma unroll
        for (int j = 0; j < 64; ++j) {
            const int c = (j + tid) & 63;  // rotate start -> conflict-free
            rs += fabsf(Sf[tid * 64 + c]);
        }
        #pragma unroll
        for (int m = 32; m > 0; m >>= 1) rs = fmaxf(rs, __shfl_xor(rs, m, 64));
        if (tid == 0) sred[0] = rs;
    }
    __syncthreads();
    const float s = sred[0];
    const float invs = 1.0f / s;

    // A = sigma/s (fp32 to Ag, bf16-hi to Ah); Z = I
    #pragma unroll
    for (int j = 0; j < 16; ++j) {
        const int e = tid * 16 + j;
        const int i = e >> 6, c = e & 63;
        const float a = Sf[e] * invs;
        Ag[e] = a;
        Ah[i * LDB + c] = f2bf(a);
        const float z = (i == c) ? 1.0f : 0.0f;
        Zf[e] = z;
        ZhA[i * LDB + c] = f2bf(z);
    }
    __syncthreads();

    // 4 plain bf16 NS iterations: Z <- 1.5 Z - 0.5 Z*(A*(Z*Z))
    for (int itn = 0; itn < 4; ++itn) {
        mm_plain(ZhA, ZhA, Bh, nullptr, tid);   // M = Z*Z
        mm_plain(Ah, Bh, Bh, nullptr, tid);     // W = A*M (in-place OK)
        mm_plain(ZhA, Bh, nullptr, Sf, tid);    // V = Z*W -> fp32
        #pragma unroll
        for (int j = 0; j < 16; ++j) {
            const int e = tid * 16 + j;
            const int i = e >> 6, c = e & 63;
            const float z = 1.5f * Zf[e] - 0.5f * Sf[e];
            Zf[e] = z;
            ZhA[i * LDB + c] = f2bf(z);
        }
        __syncthreads();
    }

    // polish: one NS step at ~fp32 precision via split-bf16 (hi*hi+hi*lo+lo*hi)
    mm_split(ZhA, Zf, ZhA, Zf, Bh, Sf, tid);     // M = Z*Z     -> (Bh, Sf)
    mm_split(Ah, Ag, Bh, Sf, Bh, Sf, tid);       // W = A*M     -> (Bh, Sf)
    mm_split(ZhA, Zf, Bh, Sf, nullptr, Sf, tid); // V = Z*W     -> Sf

    const float wsq = 1.0f / sqrtf(s);  // wm = Z / sqrt(s)
    #pragma unroll
    for (int j = 0; j < 16; ++j) {
        const int e = tid * 16 + j;
        const float z = 1.5f * Zf[e] - 0.5f * Sf[e];
        Zf[e] = z;
        wm[e] = z * wsq;
    }
    __syncthreads();

    // b = wm * mu
    if (tid < 64) {
        float acc = 0.f;
        #pragma unroll
        for (int j = 0; j < 64; ++j) {
            const int c = (j + tid) & 63;
            acc += Zf[tid * 64 + c] * mu[c];
        }
        bvec[tid] = acc * wsq;
    }
}

// ---------------------------------------------------------------------------
// K3: out[n][c][hw] = sum_c' wm[c][c'] * X[n][c'][hw] - b[c]
// wm symmetric -> read rows (contiguous, scalar-cached). 1 wave = 64 positions.
// ---------------------------------------------------------------------------
__global__ __launch_bounds__(256) void k3_whiten(const float* __restrict__ X,
                                                 const float* __restrict__ wm,
                                                 const float* __restrict__ bvec,
                                                 float* __restrict__ out) {
    const int tid = threadIdx.x;
    const int w = tid >> 6, l = tid & 63;
    const uint32_t chunk = blockIdx.x * 4u + (uint32_t)w;  // 6272 chunks, 49/image
    const uint32_t n = chunk / 49u;
    const uint32_t hw = (chunk - n * 49u) * 64u + (uint32_t)l;
    const size_t base = (size_t)n * (CCH * HWSZ) + hw;

    float acc[64];
    #pragma unroll
    for (int c = 0; c < 64; ++c) acc[c] = 0.f;

    float xv = X[base];
    for (int cp = 0; cp < 64; ++cp) {
        const float xn = (cp < 63) ? X[base + (size_t)(cp + 1) * HWSZ] : 0.f;
        const float* wr = wm + cp * 64;  // row cp == column cp (symmetric)
        #pragma unroll
        for (int c = 0; c < 64; ++c) acc[c] = fmaf(wr[c], xv, acc[c]);
        xv = xn;
    }
    #pragma unroll
    for (int c = 0; c < 64; ++c)
        out[base + (size_t)c * HWSZ] = acc[c] - bvec[c];
}

// ---------------------------------------------------------------------------
extern "C" void kernel_launch(void* const* d_in, const int* in_sizes, int n_in,
                              void* d_out, int out_size, void* d_ws, size_t ws_size,
                              hipStream_t stream) {
    (void)in_sizes; (void)n_in; (void)out_size; (void)ws_size;
    const float* X = (const float*)d_in[0];
    float* out = (float*)d_out;
    float* ws = (float*)d_ws;

    // zero gram (4096) + sums (64) accumulators
    hipMemsetAsync(d_ws, 0, 4160 * sizeof(float), stream);

    k1_gram<<<1568, 256, 0, stream>>>(X, ws, ws + 4096);
    k2_ns<<<1, 256, 0, stream>>>(ws);
    k3_whiten<<<1568, 256, 0, stream>>>(X, ws + 4160, ws + 8256, out);
}

// Round 2
// 360.787 us; speedup vs baseline: 2.3599x; 2.3599x over previous
//
#include <hip/hip_runtime.h>
#include <stdint.h>

// Problem constants
#define CCH   64
#define HWSZ  3136        // 56*56
#define NB    128
#define MCOLS 401408      // NB*HWSZ
#define TK    128         // K1 tile columns
#define NTILES 3136       // MCOLS / TK
#define LDK   136         // TK+8 bf16 stride (272 B, 16B-aligned, conflict-benign)
#define LDB   72          // K2 bf16 row stride (144 B, 16B-aligned)
#define SLOT  4160        // per-block partial: 4096 gram + 64 sums (floats)
#define WS_TAIL 12416     // gram+sums+wm+bvec+Ag floats at ws[0..)

typedef short bf16x8 __attribute__((ext_vector_type(8)));
typedef float f32x4  __attribute__((ext_vector_type(4)));

__device__ __forceinline__ unsigned short f2bf(float f) {
    union { float f; uint32_t u; } v; v.f = f;
    uint32_t r = v.u + 0x7fffu + ((v.u >> 16) & 1u);   // round-to-nearest-even
    return (unsigned short)(r >> 16);
}
__device__ __forceinline__ float bf2f(unsigned short h) {
    union { uint32_t u; float f; } v; v.u = ((uint32_t)h) << 16; return v.f;
}

// ---------------------------------------------------------------------------
// K1: per-channel sums + gram = X*X^T via bf16 MFMA (gram is symmetric =>
// immune to any C/D layout transpose). Grid-stride over tiles; each block
// writes a PRIVATE partial (no atomics — R1 showed 6.4M atomic RMWs onto the
// 16 KB gram serialized to 700 us).
// ---------------------------------------------------------------------------
__global__ __launch_bounds__(256) void k1_gram(const float* __restrict__ X,
                                               float* __restrict__ part,
                                               int nb) {
    __shared__ __align__(16) unsigned short tile[CCH * LDK];  // 17408 B
    const int tid = threadIdx.x;
    const int w = tid >> 6, l = tid & 63;

    f32x4 acc[4];
    #pragma unroll
    for (int b = 0; b < 4; ++b) acc[b] = (f32x4){0.f, 0.f, 0.f, 0.f};
    float sacc[16];
    #pragma unroll
    for (int i = 0; i < 16; ++i) sacc[i] = 0.f;

    for (uint32_t t = blockIdx.x; t < NTILES; t += (uint32_t)nb) {
        const uint32_t s = t * TK + 2u * (uint32_t)l;  // column pair start (even)
        const uint32_t n = s / HWSZ;                   // float2 never crosses n
        const uint32_t hw = s - n * HWSZ;
        const size_t base = (size_t)n * (CCH * HWSZ) + hw + (size_t)w * HWSZ;

        __syncthreads();  // protect LDS from previous tile's readers
        // stage: channel c = 4*i + w, columns s..s+1
        #pragma unroll
        for (int i = 0; i < 16; ++i) {
            const float2 xv = *(const float2*)(X + base + (size_t)i * (4u * HWSZ));
            sacc[i] += xv.x + xv.y;
            const int c = 4 * i + w;
            *(uint32_t*)&tile[c * LDK + 2 * l] =
                (uint32_t)f2bf(xv.x) | ((uint32_t)f2bf(xv.y) << 16);
        }
        __syncthreads();

        // MFMA: wave w computes gram blocks (row-block w, col-blocks 0..3)
        #pragma unroll
        for (int k0 = 0; k0 < TK; k0 += 32) {
            const int koff = k0 + ((l >> 4) << 3);
            const bf16x8 fa = *(const bf16x8*)&tile[(16 * w + (l & 15)) * LDK + koff];
            #pragma unroll
            for (int bj = 0; bj < 4; ++bj) {
                const bf16x8 fb = *(const bf16x8*)&tile[(16 * bj + (l & 15)) * LDK + koff];
                acc[bj] = __builtin_amdgcn_mfma_f32_16x16x32_bf16(fa, fb, acc[bj], 0, 0, 0);
            }
        }
    }

    // epilogue: plain stores to this block's private slot
    float* pg = part + (size_t)blockIdx.x * SLOT;
    #pragma unroll
    for (int bj = 0; bj < 4; ++bj) {
        #pragma unroll
        for (int r = 0; r < 4; ++r) {
            const int row = 16 * w + ((l >> 4) << 2) + r;
            const int col = 16 * bj + (l & 15);
            pg[row * 64 + col] = acc[bj][r];
        }
    }
    #pragma unroll
    for (int i = 0; i < 16; ++i) {
        float v = sacc[i];
        #pragma unroll
        for (int m = 32; m > 0; m >>= 1) v += __shfl_xor(v, m, 64);
        if (l == 0) pg[4096 + 4 * i + w] = v;
    }
}

// ---------------------------------------------------------------------------
// K1b: reduce nb partial slots -> ws[0..4159] (gram 4096 | sums 64).
// Consecutive threads read consecutive addresses (stride SLOT between slots).
// ---------------------------------------------------------------------------
__global__ __launch_bounds__(256) void k1b_reduce(const float* __restrict__ part,
                                                  float* __restrict__ out,
                                                  int nb) {
    const int e = blockIdx.x * 256 + threadIdx.x;
    if (e >= SLOT) return;
    float a = 0.f;
    for (int b = 0; b < nb; ++b) a += part[(size_t)b * SLOT + e];
    out[e] = a;
}

// ---------------------------------------------------------------------------
// K2 helpers: 64x64 matmuls on one workgroup via MFMA. All operands are
// symmetric (polynomials in A), so B-frags read R's rows directly.
// ---------------------------------------------------------------------------
__device__ __forceinline__ bf16x8 ldfrag_h(const unsigned short* H, int rowbase, int k0, int l) {
    const int row = rowbase + (l & 15);
    const int koff = k0 + ((l >> 4) << 3);
    return *(const bf16x8*)&H[row * LDB + koff];
}
__device__ __forceinline__ bf16x8 ldfrag_lo(const float* F, bf16x8 hi, int rowbase, int k0, int l) {
    const int row = rowbase + (l & 15);
    const int koff = k0 + ((l >> 4) << 3);
    const float* p = F + row * 64 + koff;
    bf16x8 lo;
    #pragma unroll
    for (int j = 0; j < 8; ++j)
        lo[j] = (short)f2bf(p[j] - bf2f((unsigned short)hi[j]));
    return lo;
}

__device__ void mm_plain(const unsigned short* Lh, const unsigned short* Rh,
                         unsigned short* DH, float* DF, int tid) {
    const int w = tid >> 6, l = tid & 63;
    f32x4 acc[4];
    #pragma unroll
    for (int b = 0; b < 4; ++b) acc[b] = (f32x4){0.f, 0.f, 0.f, 0.f};
    #pragma unroll
    for (int k0 = 0; k0 < 64; k0 += 32) {
        const bf16x8 la = ldfrag_h(Lh, 16 * w, k0, l);
        #pragma unroll
        for (int b = 0; b < 4; ++b) {
            const bf16x8 rb = ldfrag_h(Rh, 16 * b, k0, l);
            acc[b] = __builtin_amdgcn_mfma_f32_16x16x32_bf16(la, rb, acc[b], 0, 0, 0);
        }
    }
    __syncthreads();  // allow in-place D==R
    #pragma unroll
    for (int b = 0; b < 4; ++b) {
        #pragma unroll
        for (int r = 0; r < 4; ++r) {
            const int row = 16 * w + ((l >> 4) << 2) + r;
            const int col = 16 * b + (l & 15);
            const float v = acc[b][r];
            if (DH) DH[row * LDB + col] = f2bf(v);
            if (DF) DF[row * 64 + col] = v;
        }
    }
    __syncthreads();
}

__device__ void mm_split(const unsigned short* Lh, const float* Lf,
                         const unsigned short* Rh, const float* Rf,
                         unsigned short* DH, float* DF, int tid) {
    const int w = tid >> 6, l = tid & 63;
    f32x4 acc[4];
    #pragma unroll
    for (int b = 0; b < 4; ++b) acc[b] = (f32x4){0.f, 0.f, 0.f, 0.f};
    #pragma unroll
    for (int k0 = 0; k0 < 64; k0 += 32) {
        const bf16x8 lah = ldfrag_h(Lh, 16 * w, k0, l);
        const bf16x8 lal = ldfrag_lo(Lf, lah, 16 * w, k0, l);
        #pragma unroll
        for (int b = 0; b < 4; ++b) {
            const bf16x8 rbh = ldfrag_h(Rh, 16 * b, k0, l);
            const bf16x8 rbl = ldfrag_lo(Rf, rbh, 16 * b, k0, l);
            acc[b] = __builtin_amdgcn_mfma_f32_16x16x32_bf16(lah, rbh, acc[b], 0, 0, 0);
            acc[b] = __builtin_amdgcn_mfma_f32_16x16x32_bf16(lah, rbl, acc[b], 0, 0, 0);
            acc[b] = __builtin_amdgcn_mfma_f32_16x16x32_bf16(lal, rbh, acc[b], 0, 0, 0);
        }
    }
    __syncthreads();  // allow in-place D==R
    #pragma unroll
    for (int b = 0; b < 4; ++b) {
        #pragma unroll
        for (int r = 0; r < 4; ++r) {
            const int row = 16 * w + ((l >> 4) << 2) + r;
            const int col = 16 * b + (l & 15);
            const float v = acc[b][r];
            if (DH) DH[row * LDB + col] = f2bf(v);
            if (DF) DF[row * 64 + col] = v;
        }
    }
    __syncthreads();
}

// ---------------------------------------------------------------------------
// K2: sigma -> Newton-Schulz inverse sqrt -> wm, b. Single workgroup.
// ---------------------------------------------------------------------------
__global__ __launch_bounds__(256) void k2_ns(float* __restrict__ ws) {
    const float* gram = ws;
    const float* sums = ws + 4096;
    float* wm = ws + 4160;
    float* bvec = ws + 8256;
    float* Ag = ws + 8320;  // fp32 A = sigma/s (global, for polish lo-frags)

    __shared__ float Zf[4096];
    __shared__ float Sf[4096];
    __shared__ __align__(16) unsigned short Ah[64 * LDB];
    __shared__ __align__(16) unsigned short ZhA[64 * LDB];
    __shared__ __align__(16) unsigned short Bh[64 * LDB];
    __shared__ float mu[64];
    __shared__ float sred[1];

    const int tid = threadIdx.x;
    const float invm = 1.0f / (float)MCOLS;

    if (tid < 64) mu[tid] = sums[tid] * invm;
    __syncthreads();

    // sigma -> Sf
    #pragma unroll
    for (int j = 0; j < 16; ++j) {
        const int e = tid * 16 + j;
        const int i = e >> 6, c = e & 63;
        Sf[e] = gram[e] * invm - mu[i] * mu[c] + ((i == c) ? 1e-3f : 0.0f);
    }
    __syncthreads();

    // s = ||sigma||_inf (Gershgorin bound on lambda_max)
    if (tid < 64) {
        float rs = 0.f;
        #pragma unroll
        for (int j = 0; j < 64; ++j) {
            const int c = (j + tid) & 63;  // rotate start -> conflict-free
            rs += fabsf(Sf[tid * 64 + c]);
        }
        #pragma unroll
        for (int m = 32; m > 0; m >>= 1) rs = fmaxf(rs, __shfl_xor(rs, m, 64));
        if (tid == 0) sred[0] = rs;
    }
    __syncthreads();
    const float s = sred[0];
    const float invs = 1.0f / s;

    // A = sigma/s (fp32 to Ag, bf16-hi to Ah); Z = I
    #pragma unroll
    for (int j = 0; j < 16; ++j) {
        const int e = tid * 16 + j;
        const int i = e >> 6, c = e & 63;
        const float a = Sf[e] * invs;
        Ag[e] = a;
        Ah[i * LDB + c] = f2bf(a);
        const float z = (i == c) ? 1.0f : 0.0f;
        Zf[e] = z;
        ZhA[i * LDB + c] = f2bf(z);
    }
    __syncthreads();

    // 4 plain bf16 NS iterations: Z <- 1.5 Z - 0.5 Z*(A*(Z*Z))
    for (int itn = 0; itn < 4; ++itn) {
        mm_plain(ZhA, ZhA, Bh, nullptr, tid);   // M = Z*Z
        mm_plain(Ah, Bh, Bh, nullptr, tid);     // W = A*M (in-place OK)
        mm_plain(ZhA, Bh, nullptr, Sf, tid);    // V = Z*W -> fp32
        #pragma unroll
        for (int j = 0; j < 16; ++j) {
            const int e = tid * 16 + j;
            const int i = e >> 6, c = e & 63;
            const float z = 1.5f * Zf[e] - 0.5f * Sf[e];
            Zf[e] = z;
            ZhA[i * LDB + c] = f2bf(z);
        }
        __syncthreads();
    }

    // polish: one NS step at ~fp32 precision via split-bf16 (hi*hi+hi*lo+lo*hi)
    mm_split(ZhA, Zf, ZhA, Zf, Bh, Sf, tid);     // M = Z*Z     -> (Bh, Sf)
    mm_split(Ah, Ag, Bh, Sf, Bh, Sf, tid);       // W = A*M     -> (Bh, Sf)
    mm_split(ZhA, Zf, Bh, Sf, nullptr, Sf, tid); // V = Z*W     -> Sf

    const float wsq = 1.0f / sqrtf(s);  // wm = Z / sqrt(s)
    #pragma unroll
    for (int j = 0; j < 16; ++j) {
        const int e = tid * 16 + j;
        const float z = 1.5f * Zf[e] - 0.5f * Sf[e];
        Zf[e] = z;
        wm[e] = z * wsq;
    }
    __syncthreads();

    // b = wm * mu
    if (tid < 64) {
        float acc = 0.f;
        #pragma unroll
        for (int j = 0; j < 64; ++j) {
            const int c = (j + tid) & 63;
            acc += Zf[tid * 64 + c] * mu[c];
        }
        bvec[tid] = acc * wsq;
    }
}

// ---------------------------------------------------------------------------
// K3: out[n][c][hw] = sum_c' wm[c][c'] * X[n][c'][hw] - b[c]
// wm symmetric -> read rows (contiguous, scalar-cached). 1 wave = 64 positions.
// ---------------------------------------------------------------------------
__global__ __launch_bounds__(256) void k3_whiten(const float* __restrict__ X,
                                                 const float* __restrict__ wm,
                                                 const float* __restrict__ bvec,
                                                 float* __restrict__ out) {
    const int tid = threadIdx.x;
    const int w = tid >> 6, l = tid & 63;
    const uint32_t chunk = blockIdx.x * 4u + (uint32_t)w;  // 6272 chunks, 49/image
    const uint32_t n = chunk / 49u;
    const uint32_t hw = (chunk - n * 49u) * 64u + (uint32_t)l;
    const size_t base = (size_t)n * (CCH * HWSZ) + hw;

    float acc[64];
    #pragma unroll
    for (int c = 0; c < 64; ++c) acc[c] = 0.f;

    float xv = X[base];
    for (int cp = 0; cp < 64; ++cp) {
        const float xn = (cp < 63) ? X[base + (size_t)(cp + 1) * HWSZ] : 0.f;
        const float* wr = wm + cp * 64;  // row cp == column cp (symmetric)
        #pragma unroll
        for (int c = 0; c < 64; ++c) acc[c] = fmaf(wr[c], xv, acc[c]);
        xv = xn;
    }
    #pragma unroll
    for (int c = 0; c < 64; ++c)
        out[base + (size_t)c * HWSZ] = acc[c] - bvec[c];
}

// ---------------------------------------------------------------------------
extern "C" void kernel_launch(void* const* d_in, const int* in_sizes, int n_in,
                              void* d_out, int out_size, void* d_ws, size_t ws_size,
                              hipStream_t stream) {
    (void)in_sizes; (void)n_in; (void)out_size;
    const float* X = (const float*)d_in[0];
    float* out = (float*)d_out;
    float* ws = (float*)d_ws;

    // Adaptive K1 grid: each block needs a SLOT-float private partial in ws.
    long avail = (long)(ws_size / sizeof(float)) - WS_TAIL;
    int nb = (int)(avail / SLOT);
    if (nb > 448) nb = 448;
    if (nb < 1) nb = 1;

    float* part = ws + WS_TAIL;

    k1_gram<<<nb, 256, 0, stream>>>(X, part, nb);
    k1b_reduce<<<(SLOT + 255) / 256, 256, 0, stream>>>(part, ws, nb);
    k2_ns<<<1, 256, 0, stream>>>(ws);
    k3_whiten<<<1568, 256, 0, stream>>>(X, ws + 4160, ws + 8256, out);
}

// Round 3
// 269.623 us; speedup vs baseline: 3.1578x; 1.3381x over previous
//
#include <hip/hip_runtime.h>
#include <stdint.h>

// Problem constants
#define CCH   64
#define HWSZ  3136        // 56*56
#define NB    128
#define MCOLS 401408      // NB*HWSZ
#define TK    128         // K1 tile columns
#define NTILES 3136       // MCOLS / TK
#define LDK   136         // TK+8 bf16 stride (272 B, 16B-aligned, conflict-benign)
#define LDB   72          // K2 bf16 row stride (144 B, 16B-aligned)
#define SLOT  4160        // per-block partial: 4096 gram + 64 sums (floats)
#define WS_TAIL 12416     // gram+sums+wm+bvec+Ag floats at ws[0..)
#define RG    32          // reduction tree fan-in groups
#define K1MAX 1024        // k1 grid cap: 4 blocks/CU, 3-4 tiles/block

typedef short bf16x8 __attribute__((ext_vector_type(8)));
typedef float f32x4  __attribute__((ext_vector_type(4)));

__device__ __forceinline__ unsigned short f2bf(float f) {
    union { float f; uint32_t u; } v; v.f = f;
    uint32_t r = v.u + 0x7fffu + ((v.u >> 16) & 1u);   // round-to-nearest-even
    return (unsigned short)(r >> 16);
}
__device__ __forceinline__ float bf2f(unsigned short h) {
    union { uint32_t u; float f; } v; v.u = ((uint32_t)h) << 16; return v.f;
}

// ---------------------------------------------------------------------------
// K1: per-channel sums + gram = X*X^T via bf16 MFMA (gram symmetric => immune
// to C/D transpose). Grid-stride over tiles, private per-block partials (no
// atomics — R1: 6.4M RMWs on 16KB serialized to 700us). R3: register-prefetch
// pipeline (issue next tile's loads before the MFMA section) + 1024 blocks.
// ---------------------------------------------------------------------------
__global__ __launch_bounds__(256) void k1_gram(const float* __restrict__ X,
                                               float* __restrict__ part,
                                               int nb) {
    __shared__ __align__(16) unsigned short tile[CCH * LDK];  // 17408 B
    const int tid = threadIdx.x;
    const int w = tid >> 6, l = tid & 63;

    f32x4 acc[4];
    #pragma unroll
    for (int b = 0; b < 4; ++b) acc[b] = (f32x4){0.f, 0.f, 0.f, 0.f};
    float sacc[16];
    #pragma unroll
    for (int i = 0; i < 16; ++i) sacc[i] = 0.f;

    float2 xv[16];

    // prologue: load first tile into registers
    uint32_t t = blockIdx.x;
    {
        const uint32_t s = t * TK + 2u * (uint32_t)l;  // even => float2 never crosses n
        const uint32_t n = s / HWSZ;
        const uint32_t hw = s - n * HWSZ;
        const size_t base = (size_t)n * (CCH * HWSZ) + hw + (size_t)w * HWSZ;
        #pragma unroll
        for (int i = 0; i < 16; ++i)
            xv[i] = *(const float2*)(X + base + (size_t)i * (4u * HWSZ));
    }

    for (;;) {
        __syncthreads();  // previous tile's LDS readers done
        // stage registers -> LDS (channel c = 4*i + w)
        #pragma unroll
        for (int i = 0; i < 16; ++i) {
            sacc[i] += xv[i].x + xv[i].y;
            const int c = 4 * i + w;
            *(uint32_t*)&tile[c * LDK + 2 * l] =
                (uint32_t)f2bf(xv[i].x) | ((uint32_t)f2bf(xv[i].y) << 16);
        }
        __syncthreads();

        // prefetch next tile (loads overlap the MFMA section below)
        const uint32_t tn = t + (uint32_t)nb;
        const bool more = tn < NTILES;
        if (more) {
            const uint32_t s = tn * TK + 2u * (uint32_t)l;
            const uint32_t n = s / HWSZ;
            const uint32_t hw = s - n * HWSZ;
            const size_t base = (size_t)n * (CCH * HWSZ) + hw + (size_t)w * HWSZ;
            #pragma unroll
            for (int i = 0; i < 16; ++i)
                xv[i] = *(const float2*)(X + base + (size_t)i * (4u * HWSZ));
        }

        // MFMA: wave w computes gram row-block w x col-blocks 0..3
        #pragma unroll
        for (int k0 = 0; k0 < TK; k0 += 32) {
            const int koff = k0 + ((l >> 4) << 3);
            const bf16x8 fa = *(const bf16x8*)&tile[(16 * w + (l & 15)) * LDK + koff];
            #pragma unroll
            for (int bj = 0; bj < 4; ++bj) {
                const bf16x8 fb = *(const bf16x8*)&tile[(16 * bj + (l & 15)) * LDK + koff];
                acc[bj] = __builtin_amdgcn_mfma_f32_16x16x32_bf16(fa, fb, acc[bj], 0, 0, 0);
            }
        }

        if (!more) break;
        t = tn;
    }

    // epilogue: plain stores to this block's private slot
    float* pg = part + (size_t)blockIdx.x * SLOT;
    #pragma unroll
    for (int bj = 0; bj < 4; ++bj) {
        #pragma unroll
        for (int r = 0; r < 4; ++r) {
            const int row = 16 * w + ((l >> 4) << 2) + r;
            const int col = 16 * bj + (l & 15);
            pg[row * 64 + col] = acc[bj][r];
        }
    }
    #pragma unroll
    for (int i = 0; i < 16; ++i) {
        float v = sacc[i];
        #pragma unroll
        for (int m = 32; m > 0; m >>= 1) v += __shfl_xor(v, m, 64);
        if (l == 0) pg[4096 + 4 * i + w] = v;
    }
}

// ---------------------------------------------------------------------------
// K1b stage 1: 17*RG blocks. Block (g = bx/17) sums slots {g, g+RG, ...} into
// part2[g]. 4 independent accumulators break the R2 dependent-load chain
// (R2: 17 blocks x 448 serial loads = 107us latency-bound).
// ---------------------------------------------------------------------------
__global__ __launch_bounds__(256) void k1b1_reduce(const float* __restrict__ part,
                                                   float* __restrict__ part2,
                                                   int nb) {
    const int bx = blockIdx.x;
    const int g = bx / 17;
    const int e = (bx - g * 17) * 256 + threadIdx.x;
    if (e >= SLOT) return;
    float a0 = 0.f, a1 = 0.f, a2 = 0.f, a3 = 0.f;
    int b = g;
    for (; b + 3 * RG < nb; b += 4 * RG) {
        a0 += part[(size_t)b * SLOT + e];
        a1 += part[(size_t)(b + RG) * SLOT + e];
        a2 += part[(size_t)(b + 2 * RG) * SLOT + e];
        a3 += part[(size_t)(b + 3 * RG) * SLOT + e];
    }
    for (; b < nb; b += RG) a0 += part[(size_t)b * SLOT + e];
    part2[(size_t)g * SLOT + e] = (a0 + a1) + (a2 + a3);
}

// K1b stage 2: fold RG group-partials -> ws[0..4159] (gram 4096 | sums 64)
__global__ __launch_bounds__(256) void k1b2_reduce(const float* __restrict__ part2,
                                                   float* __restrict__ out) {
    const int e = blockIdx.x * 256 + threadIdx.x;
    if (e >= SLOT) return;
    float a0 = 0.f, a1 = 0.f, a2 = 0.f, a3 = 0.f;
    #pragma unroll
    for (int b = 0; b < RG; b += 4) {
        a0 += part2[(size_t)b * SLOT + e];
        a1 += part2[(size_t)(b + 1) * SLOT + e];
        a2 += part2[(size_t)(b + 2) * SLOT + e];
        a3 += part2[(size_t)(b + 3) * SLOT + e];
    }
    out[e] = (a0 + a1) + (a2 + a3);
}

// ---------------------------------------------------------------------------
// K2 helpers: 64x64 matmuls on one workgroup via MFMA. All operands are
// symmetric (polynomials in A), so B-frags read R's rows directly.
// ---------------------------------------------------------------------------
__device__ __forceinline__ bf16x8 ldfrag_h(const unsigned short* H, int rowbase, int k0, int l) {
    const int row = rowbase + (l & 15);
    const int koff = k0 + ((l >> 4) << 3);
    return *(const bf16x8*)&H[row * LDB + koff];
}
__device__ __forceinline__ bf16x8 ldfrag_lo(const float* F, bf16x8 hi, int rowbase, int k0, int l) {
    const int row = rowbase + (l & 15);
    const int koff = k0 + ((l >> 4) << 3);
    const float* p = F + row * 64 + koff;
    bf16x8 lo;
    #pragma unroll
    for (int j = 0; j < 8; ++j)
        lo[j] = (short)f2bf(p[j] - bf2f((unsigned short)hi[j]));
    return lo;
}

__device__ void mm_plain(const unsigned short* Lh, const unsigned short* Rh,
                         unsigned short* DH, float* DF, int tid) {
    const int w = tid >> 6, l = tid & 63;
    f32x4 acc[4];
    #pragma unroll
    for (int b = 0; b < 4; ++b) acc[b] = (f32x4){0.f, 0.f, 0.f, 0.f};
    #pragma unroll
    for (int k0 = 0; k0 < 64; k0 += 32) {
        const bf16x8 la = ldfrag_h(Lh, 16 * w, k0, l);
        #pragma unroll
        for (int b = 0; b < 4; ++b) {
            const bf16x8 rb = ldfrag_h(Rh, 16 * b, k0, l);
            acc[b] = __builtin_amdgcn_mfma_f32_16x16x32_bf16(la, rb, acc[b], 0, 0, 0);
        }
    }
    __syncthreads();  // allow in-place D==R
    #pragma unroll
    for (int b = 0; b < 4; ++b) {
        #pragma unroll
        for (int r = 0; r < 4; ++r) {
            const int row = 16 * w + ((l >> 4) << 2) + r;
            const int col = 16 * b + (l & 15);
            const float v = acc[b][r];
            if (DH) DH[row * LDB + col] = f2bf(v);
            if (DF) DF[row * 64 + col] = v;
        }
    }
    __syncthreads();
}

__device__ void mm_split(const unsigned short* Lh, const float* Lf,
                         const unsigned short* Rh, const float* Rf,
                         unsigned short* DH, float* DF, int tid) {
    const int w = tid >> 6, l = tid & 63;
    f32x4 acc[4];
    #pragma unroll
    for (int b = 0; b < 4; ++b) acc[b] = (f32x4){0.f, 0.f, 0.f, 0.f};
    #pragma unroll
    for (int k0 = 0; k0 < 64; k0 += 32) {
        const bf16x8 lah = ldfrag_h(Lh, 16 * w, k0, l);
        const bf16x8 lal = ldfrag_lo(Lf, lah, 16 * w, k0, l);
        #pragma unroll
        for (int b = 0; b < 4; ++b) {
            const bf16x8 rbh = ldfrag_h(Rh, 16 * b, k0, l);
            const bf16x8 rbl = ldfrag_lo(Rf, rbh, 16 * b, k0, l);
            acc[b] = __builtin_amdgcn_mfma_f32_16x16x32_bf16(lah, rbh, acc[b], 0, 0, 0);
            acc[b] = __builtin_amdgcn_mfma_f32_16x16x32_bf16(lah, rbl, acc[b], 0, 0, 0);
            acc[b] = __builtin_amdgcn_mfma_f32_16x16x32_bf16(lal, rbh, acc[b], 0, 0, 0);
        }
    }
    __syncthreads();  // allow in-place D==R
    #pragma unroll
    for (int b = 0; b < 4; ++b) {
        #pragma unroll
        for (int r = 0; r < 4; ++r) {
            const int row = 16 * w + ((l >> 4) << 2) + r;
            const int col = 16 * b + (l & 15);
            const float v = acc[b][r];
            if (DH) DH[row * LDB + col] = f2bf(v);
            if (DF) DF[row * 64 + col] = v;
        }
    }
    __syncthreads();
}

// ---------------------------------------------------------------------------
// K2: sigma -> Newton-Schulz inverse sqrt -> wm, b. Single workgroup.
// ---------------------------------------------------------------------------
__global__ __launch_bounds__(256) void k2_ns(float* __restrict__ ws) {
    const float* gram = ws;
    const float* sums = ws + 4096;
    float* wm = ws + 4160;
    float* bvec = ws + 8256;
    float* Ag = ws + 8320;  // fp32 A = sigma/s (global, for polish lo-frags)

    __shared__ float Zf[4096];
    __shared__ float Sf[4096];
    __shared__ __align__(16) unsigned short Ah[64 * LDB];
    __shared__ __align__(16) unsigned short ZhA[64 * LDB];
    __shared__ __align__(16) unsigned short Bh[64 * LDB];
    __shared__ float mu[64];
    __shared__ float sred[1];

    const int tid = threadIdx.x;
    const float invm = 1.0f / (float)MCOLS;

    if (tid < 64) mu[tid] = sums[tid] * invm;
    __syncthreads();

    // sigma -> Sf
    #pragma unroll
    for (int j = 0; j < 16; ++j) {
        const int e = tid * 16 + j;
        const int i = e >> 6, c = e & 63;
        Sf[e] = gram[e] * invm - mu[i] * mu[c] + ((i == c) ? 1e-3f : 0.0f);
    }
    __syncthreads();

    // s = ||sigma||_inf (Gershgorin bound on lambda_max)
    if (tid < 64) {
        float rs = 0.f;
        #pragma unroll
        for (int j = 0; j < 64; ++j) {
            const int c = (j + tid) & 63;  // rotate start -> conflict-free
            rs += fabsf(Sf[tid * 64 + c]);
        }
        #pragma unroll
        for (int m = 32; m > 0; m >>= 1) rs = fmaxf(rs, __shfl_xor(rs, m, 64));
        if (tid == 0) sred[0] = rs;
    }
    __syncthreads();
    const float s = sred[0];
    const float invs = 1.0f / s;

    // A = sigma/s (fp32 to Ag, bf16-hi to Ah); Z = I
    #pragma unroll
    for (int j = 0; j < 16; ++j) {
        const int e = tid * 16 + j;
        const int i = e >> 6, c = e & 63;
        const float a = Sf[e] * invs;
        Ag[e] = a;
        Ah[i * LDB + c] = f2bf(a);
        const float z = (i == c) ? 1.0f : 0.0f;
        Zf[e] = z;
        ZhA[i * LDB + c] = f2bf(z);
    }
    __syncthreads();

    // 4 plain bf16 NS iterations: Z <- 1.5 Z - 0.5 Z*(A*(Z*Z))
    for (int itn = 0; itn < 4; ++itn) {
        mm_plain(ZhA, ZhA, Bh, nullptr, tid);   // M = Z*Z
        mm_plain(Ah, Bh, Bh, nullptr, tid);     // W = A*M (in-place OK)
        mm_plain(ZhA, Bh, nullptr, Sf, tid);    // V = Z*W -> fp32
        #pragma unroll
        for (int j = 0; j < 16; ++j) {
            const int e = tid * 16 + j;
            const int i = e >> 6, c = e & 63;
            const float z = 1.5f * Zf[e] - 0.5f * Sf[e];
            Zf[e] = z;
            ZhA[i * LDB + c] = f2bf(z);
        }
        __syncthreads();
    }

    // polish: one NS step at ~fp32 precision via split-bf16 (hi*hi+hi*lo+lo*hi)
    mm_split(ZhA, Zf, ZhA, Zf, Bh, Sf, tid);     // M = Z*Z     -> (Bh, Sf)
    mm_split(Ah, Ag, Bh, Sf, Bh, Sf, tid);       // W = A*M     -> (Bh, Sf)
    mm_split(ZhA, Zf, Bh, Sf, nullptr, Sf, tid); // V = Z*W     -> Sf

    const float wsq = 1.0f / sqrtf(s);  // wm = Z / sqrt(s)
    #pragma unroll
    for (int j = 0; j < 16; ++j) {
        const int e = tid * 16 + j;
        const float z = 1.5f * Zf[e] - 0.5f * Sf[e];
        Zf[e] = z;
        wm[e] = z * wsq;
    }
    __syncthreads();

    // b = wm * mu
    if (tid < 64) {
        float acc = 0.f;
        #pragma unroll
        for (int j = 0; j < 64; ++j) {
            const int c = (j + tid) & 63;
            acc += Zf[tid * 64 + c] * mu[c];
        }
        bvec[tid] = acc * wsq;
    }
}

// ---------------------------------------------------------------------------
// K3: out[n][c][hw] = sum_c' wm[c][c'] * X[n][c'][hw] - b[c]
// wm symmetric -> read rows (contiguous, scalar-cached). 1 wave = 64 positions.
// ---------------------------------------------------------------------------
__global__ __launch_bounds__(256) void k3_whiten(const float* __restrict__ X,
                                                 const float* __restrict__ wm,
                                                 const float* __restrict__ bvec,
                                                 float* __restrict__ out) {
    const int tid = threadIdx.x;
    const int w = tid >> 6, l = tid & 63;
    const uint32_t chunk = blockIdx.x * 4u + (uint32_t)w;  // 6272 chunks, 49/image
    const uint32_t n = chunk / 49u;
    const uint32_t hw = (chunk - n * 49u) * 64u + (uint32_t)l;
    const size_t base = (size_t)n * (CCH * HWSZ) + hw;

    float acc[64];
    #pragma unroll
    for (int c = 0; c < 64; ++c) acc[c] = 0.f;

    float xv = X[base];
    for (int cp = 0; cp < 64; ++cp) {
        const float xn = (cp < 63) ? X[base + (size_t)(cp + 1) * HWSZ] : 0.f;
        const float* wr = wm + cp * 64;  // row cp == column cp (symmetric)
        #pragma unroll
        for (int c = 0; c < 64; ++c) acc[c] = fmaf(wr[c], xv, acc[c]);
        xv = xn;
    }
    #pragma unroll
    for (int c = 0; c < 64; ++c)
        out[base + (size_t)c * HWSZ] = acc[c] - bvec[c];
}

// ---------------------------------------------------------------------------
extern "C" void kernel_launch(void* const* d_in, const int* in_sizes, int n_in,
                              void* d_out, int out_size, void* d_ws, size_t ws_size,
                              hipStream_t stream) {
    (void)in_sizes; (void)n_in; (void)out_size;
    const float* X = (const float*)d_in[0];
    float* out = (float*)d_out;
    float* ws = (float*)d_ws;

    // ws layout: [0..WS_TAIL) result area | nb K1 slots | RG stage-2 slots
    long avail = (long)(ws_size / sizeof(float)) - WS_TAIL - (long)RG * SLOT;
    int nb = (int)(avail / SLOT);
    if (nb > K1MAX) nb = K1MAX;
    if (nb < 1) nb = 1;

    float* part = ws + WS_TAIL;
    float* part2 = part + (size_t)nb * SLOT;

    k1_gram<<<nb, 256, 0, stream>>>(X, part, nb);
    k1b1_reduce<<<17 * RG, 256, 0, stream>>>(part, part2, nb);
    k1b2_reduce<<<17, 256, 0, stream>>>(part2, ws);
    k2_ns<<<1, 256, 0, stream>>>(ws);
    k3_whiten<<<1568, 256, 0, stream>>>(X, ws + 4160, ws + 8256, out);
}

// Round 4
// 251.123 us; speedup vs baseline: 3.3905x; 1.0737x over previous
//
#include <hip/hip_runtime.h>
#include <stdint.h>

// Problem constants
#define CCH   64
#define HWSZ  3136        // 56*56
#define NB    128
#define MCOLS 401408      // NB*HWSZ
#define TK    128         // K1 tile columns
#define NTILES 3136       // MCOLS / TK
#define LDK   136         // TK+8 bf16 stride (272 B, 16B-aligned, conflict-benign)
#define LDB   72          // K2 bf16 row stride (144 B, 16B-aligned)
#define SLOT  4160        // per-block partial: 4096 gram + 64 sums (floats)
#define WS_TAIL 12416     // gram+sums+wm+bvec+Ag floats at ws[0..)
#define RG    32          // reduction tree fan-in groups
#define K1MAX 1024        // k1 grid cap: 4 blocks/CU, 3-4 tiles/block

typedef short bf16x8 __attribute__((ext_vector_type(8)));
typedef float f32x4  __attribute__((ext_vector_type(4)));

__device__ __forceinline__ unsigned short f2bf(float f) {
    union { float f; uint32_t u; } v; v.f = f;
    uint32_t r = v.u + 0x7fffu + ((v.u >> 16) & 1u);   // round-to-nearest-even
    return (unsigned short)(r >> 16);
}
__device__ __forceinline__ float bf2f(unsigned short h) {
    union { uint32_t u; float f; } v; v.u = ((uint32_t)h) << 16; return v.f;
}

// ---------------------------------------------------------------------------
// K1: per-channel sums + gram = X*X^T via bf16 MFMA (gram symmetric => immune
// to C/D transpose). Grid-stride over tiles, private per-block partials (no
// atomics — R1: 6.4M RMWs on 16KB serialized to 700us). Register-prefetch
// pipeline (next tile's loads issued before the MFMA section).
// ---------------------------------------------------------------------------
__global__ __launch_bounds__(256) void k1_gram(const float* __restrict__ X,
                                               float* __restrict__ part,
                                               int nb) {
    __shared__ __align__(16) unsigned short tile[CCH * LDK];  // 17408 B
    const int tid = threadIdx.x;
    const int w = tid >> 6, l = tid & 63;

    f32x4 acc[4];
    #pragma unroll
    for (int b = 0; b < 4; ++b) acc[b] = (f32x4){0.f, 0.f, 0.f, 0.f};
    float sacc[16];
    #pragma unroll
    for (int i = 0; i < 16; ++i) sacc[i] = 0.f;

    float2 xv[16];

    // prologue: load first tile into registers
    uint32_t t = blockIdx.x;
    {
        const uint32_t s = t * TK + 2u * (uint32_t)l;  // even => float2 never crosses n
        const uint32_t n = s / HWSZ;
        const uint32_t hw = s - n * HWSZ;
        const size_t base = (size_t)n * (CCH * HWSZ) + hw + (size_t)w * HWSZ;
        #pragma unroll
        for (int i = 0; i < 16; ++i)
            xv[i] = *(const float2*)(X + base + (size_t)i * (4u * HWSZ));
    }

    for (;;) {
        __syncthreads();  // previous tile's LDS readers done
        // stage registers -> LDS (channel c = 4*i + w)
        #pragma unroll
        for (int i = 0; i < 16; ++i) {
            sacc[i] += xv[i].x + xv[i].y;
            const int c = 4 * i + w;
            *(uint32_t*)&tile[c * LDK + 2 * l] =
                (uint32_t)f2bf(xv[i].x) | ((uint32_t)f2bf(xv[i].y) << 16);
        }
        __syncthreads();

        // prefetch next tile (loads overlap the MFMA section below)
        const uint32_t tn = t + (uint32_t)nb;
        const bool more = tn < NTILES;
        if (more) {
            const uint32_t s = tn * TK + 2u * (uint32_t)l;
            const uint32_t n = s / HWSZ;
            const uint32_t hw = s - n * HWSZ;
            const size_t base = (size_t)n * (CCH * HWSZ) + hw + (size_t)w * HWSZ;
            #pragma unroll
            for (int i = 0; i < 16; ++i)
                xv[i] = *(const float2*)(X + base + (size_t)i * (4u * HWSZ));
        }

        // MFMA: wave w computes gram row-block w x col-blocks 0..3
        #pragma unroll
        for (int k0 = 0; k0 < TK; k0 += 32) {
            const int koff = k0 + ((l >> 4) << 3);
            const bf16x8 fa = *(const bf16x8*)&tile[(16 * w + (l & 15)) * LDK + koff];
            #pragma unroll
            for (int bj = 0; bj < 4; ++bj) {
                const bf16x8 fb = *(const bf16x8*)&tile[(16 * bj + (l & 15)) * LDK + koff];
                acc[bj] = __builtin_amdgcn_mfma_f32_16x16x32_bf16(fa, fb, acc[bj], 0, 0, 0);
            }
        }

        if (!more) break;
        t = tn;
    }

    // epilogue: plain stores to this block's private slot
    float* pg = part + (size_t)blockIdx.x * SLOT;
    #pragma unroll
    for (int bj = 0; bj < 4; ++bj) {
        #pragma unroll
        for (int r = 0; r < 4; ++r) {
            const int row = 16 * w + ((l >> 4) << 2) + r;
            const int col = 16 * bj + (l & 15);
            pg[row * 64 + col] = acc[bj][r];
        }
    }
    #pragma unroll
    for (int i = 0; i < 16; ++i) {
        float v = sacc[i];
        #pragma unroll
        for (int m = 32; m > 0; m >>= 1) v += __shfl_xor(v, m, 64);
        if (l == 0) pg[4096 + 4 * i + w] = v;
    }
}

// ---------------------------------------------------------------------------
// K1b stage 1: 17*RG blocks. Block (g = bx/17) sums slots {g, g+RG, ...} into
// part2[g]. 4 independent accumulators break the R2 dependent-load chain
// (R2: 17 blocks x 448 serial loads = 107us latency-bound).
// ---------------------------------------------------------------------------
__global__ __launch_bounds__(256) void k1b1_reduce(const float* __restrict__ part,
                                                   float* __restrict__ part2,
                                                   int nb) {
    const int bx = blockIdx.x;
    const int g = bx / 17;
    const int e = (bx - g * 17) * 256 + threadIdx.x;
    if (e >= SLOT) return;
    float a0 = 0.f, a1 = 0.f, a2 = 0.f, a3 = 0.f;
    int b = g;
    for (; b + 3 * RG < nb; b += 4 * RG) {
        a0 += part[(size_t)b * SLOT + e];
        a1 += part[(size_t)(b + RG) * SLOT + e];
        a2 += part[(size_t)(b + 2 * RG) * SLOT + e];
        a3 += part[(size_t)(b + 3 * RG) * SLOT + e];
    }
    for (; b < nb; b += RG) a0 += part[(size_t)b * SLOT + e];
    part2[(size_t)g * SLOT + e] = (a0 + a1) + (a2 + a3);
}

// K1b stage 2: fold RG group-partials -> ws[0..4159] (gram 4096 | sums 64)
__global__ __launch_bounds__(256) void k1b2_reduce(const float* __restrict__ part2,
                                                   float* __restrict__ out) {
    const int e = blockIdx.x * 256 + threadIdx.x;
    if (e >= SLOT) return;
    float a0 = 0.f, a1 = 0.f, a2 = 0.f, a3 = 0.f;
    #pragma unroll
    for (int b = 0; b < RG; b += 4) {
        a0 += part2[(size_t)b * SLOT + e];
        a1 += part2[(size_t)(b + 1) * SLOT + e];
        a2 += part2[(size_t)(b + 2) * SLOT + e];
        a3 += part2[(size_t)(b + 3) * SLOT + e];
    }
    out[e] = (a0 + a1) + (a2 + a3);
}

// ---------------------------------------------------------------------------
// K2 helpers: 64x64 matmuls on one workgroup via MFMA. All operands are
// symmetric (polynomials in A), so B-frags read R's rows directly.
// ---------------------------------------------------------------------------
__device__ __forceinline__ bf16x8 ldfrag_h(const unsigned short* H, int rowbase, int k0, int l) {
    const int row = rowbase + (l & 15);
    const int koff = k0 + ((l >> 4) << 3);
    return *(const bf16x8*)&H[row * LDB + koff];
}
__device__ __forceinline__ bf16x8 ldfrag_lo(const float* F, bf16x8 hi, int rowbase, int k0, int l) {
    const int row = rowbase + (l & 15);
    const int koff = k0 + ((l >> 4) << 3);
    const float* p = F + row * 64 + koff;
    bf16x8 lo;
    #pragma unroll
    for (int j = 0; j < 8; ++j)
        lo[j] = (short)f2bf(p[j] - bf2f((unsigned short)hi[j]));
    return lo;
}

__device__ void mm_plain(const unsigned short* Lh, const unsigned short* Rh,
                         unsigned short* DH, float* DF, int tid) {
    const int w = tid >> 6, l = tid & 63;
    f32x4 acc[4];
    #pragma unroll
    for (int b = 0; b < 4; ++b) acc[b] = (f32x4){0.f, 0.f, 0.f, 0.f};
    #pragma unroll
    for (int k0 = 0; k0 < 64; k0 += 32) {
        const bf16x8 la = ldfrag_h(Lh, 16 * w, k0, l);
        #pragma unroll
        for (int b = 0; b < 4; ++b) {
            const bf16x8 rb = ldfrag_h(Rh, 16 * b, k0, l);
            acc[b] = __builtin_amdgcn_mfma_f32_16x16x32_bf16(la, rb, acc[b], 0, 0, 0);
        }
    }
    __syncthreads();  // allow in-place D==R
    #pragma unroll
    for (int b = 0; b < 4; ++b) {
        #pragma unroll
        for (int r = 0; r < 4; ++r) {
            const int row = 16 * w + ((l >> 4) << 2) + r;
            const int col = 16 * b + (l & 15);
            const float v = acc[b][r];
            if (DH) DH[row * LDB + col] = f2bf(v);
            if (DF) DF[row * 64 + col] = v;
        }
    }
    __syncthreads();
}

__device__ void mm_split(const unsigned short* Lh, const float* Lf,
                         const unsigned short* Rh, const float* Rf,
                         unsigned short* DH, float* DF, int tid) {
    const int w = tid >> 6, l = tid & 63;
    f32x4 acc[4];
    #pragma unroll
    for (int b = 0; b < 4; ++b) acc[b] = (f32x4){0.f, 0.f, 0.f, 0.f};
    #pragma unroll
    for (int k0 = 0; k0 < 64; k0 += 32) {
        const bf16x8 lah = ldfrag_h(Lh, 16 * w, k0, l);
        const bf16x8 lal = ldfrag_lo(Lf, lah, 16 * w, k0, l);
        #pragma unroll
        for (int b = 0; b < 4; ++b) {
            const bf16x8 rbh = ldfrag_h(Rh, 16 * b, k0, l);
            const bf16x8 rbl = ldfrag_lo(Rf, rbh, 16 * b, k0, l);
            acc[b] = __builtin_amdgcn_mfma_f32_16x16x32_bf16(lah, rbh, acc[b], 0, 0, 0);
            acc[b] = __builtin_amdgcn_mfma_f32_16x16x32_bf16(lah, rbl, acc[b], 0, 0, 0);
            acc[b] = __builtin_amdgcn_mfma_f32_16x16x32_bf16(lal, rbh, acc[b], 0, 0, 0);
        }
    }
    __syncthreads();  // allow in-place D==R
    #pragma unroll
    for (int b = 0; b < 4; ++b) {
        #pragma unroll
        for (int r = 0; r < 4; ++r) {
            const int row = 16 * w + ((l >> 4) << 2) + r;
            const int col = 16 * b + (l & 15);
            const float v = acc[b][r];
            if (DH) DH[row * LDB + col] = f2bf(v);
            if (DF) DF[row * 64 + col] = v;
        }
    }
    __syncthreads();
}

// ---------------------------------------------------------------------------
// K2: sigma -> Newton-Schulz inverse sqrt -> wm, b. Single workgroup.
// ---------------------------------------------------------------------------
__global__ __launch_bounds__(256) void k2_ns(float* __restrict__ ws) {
    const float* gram = ws;
    const float* sums = ws + 4096;
    float* wm = ws + 4160;
    float* bvec = ws + 8256;
    float* Ag = ws + 8320;  // fp32 A = sigma/s (global, for polish lo-frags)

    __shared__ float Zf[4096];
    __shared__ float Sf[4096];
    __shared__ __align__(16) unsigned short Ah[64 * LDB];
    __shared__ __align__(16) unsigned short ZhA[64 * LDB];
    __shared__ __align__(16) unsigned short Bh[64 * LDB];
    __shared__ float mu[64];
    __shared__ float sred[1];

    const int tid = threadIdx.x;
    const float invm = 1.0f / (float)MCOLS;

    if (tid < 64) mu[tid] = sums[tid] * invm;
    __syncthreads();

    // sigma -> Sf
    #pragma unroll
    for (int j = 0; j < 16; ++j) {
        const int e = tid * 16 + j;
        const int i = e >> 6, c = e & 63;
        Sf[e] = gram[e] * invm - mu[i] * mu[c] + ((i == c) ? 1e-3f : 0.0f);
    }
    __syncthreads();

    // s = ||sigma||_inf (Gershgorin bound on lambda_max)
    if (tid < 64) {
        float rs = 0.f;
        #pragma unroll
        for (int j = 0; j < 64; ++j) {
            const int c = (j + tid) & 63;  // rotate start -> conflict-free
            rs += fabsf(Sf[tid * 64 + c]);
        }
        #pragma unroll
        for (int m = 32; m > 0; m >>= 1) rs = fmaxf(rs, __shfl_xor(rs, m, 64));
        if (tid == 0) sred[0] = rs;
    }
    __syncthreads();
    const float s = sred[0];
    const float invs = 1.0f / s;

    // A = sigma/s (fp32 to Ag, bf16-hi to Ah); Z = I
    #pragma unroll
    for (int j = 0; j < 16; ++j) {
        const int e = tid * 16 + j;
        const int i = e >> 6, c = e & 63;
        const float a = Sf[e] * invs;
        Ag[e] = a;
        Ah[i * LDB + c] = f2bf(a);
        const float z = (i == c) ? 1.0f : 0.0f;
        Zf[e] = z;
        ZhA[i * LDB + c] = f2bf(z);
    }
    __syncthreads();

    // 4 plain bf16 NS iterations: Z <- 1.5 Z - 0.5 Z*(A*(Z*Z))
    for (int itn = 0; itn < 4; ++itn) {
        mm_plain(ZhA, ZhA, Bh, nullptr, tid);   // M = Z*Z
        mm_plain(Ah, Bh, Bh, nullptr, tid);     // W = A*M (in-place OK)
        mm_plain(ZhA, Bh, nullptr, Sf, tid);    // V = Z*W -> fp32
        #pragma unroll
        for (int j = 0; j < 16; ++j) {
            const int e = tid * 16 + j;
            const int i = e >> 6, c = e & 63;
            const float z = 1.5f * Zf[e] - 0.5f * Sf[e];
            Zf[e] = z;
            ZhA[i * LDB + c] = f2bf(z);
        }
        __syncthreads();
    }

    // polish: one NS step at ~fp32 precision via split-bf16 (hi*hi+hi*lo+lo*hi)
    mm_split(ZhA, Zf, ZhA, Zf, Bh, Sf, tid);     // M = Z*Z     -> (Bh, Sf)
    mm_split(Ah, Ag, Bh, Sf, Bh, Sf, tid);       // W = A*M     -> (Bh, Sf)
    mm_split(ZhA, Zf, Bh, Sf, nullptr, Sf, tid); // V = Z*W     -> Sf

    const float wsq = 1.0f / sqrtf(s);  // wm = Z / sqrt(s)
    #pragma unroll
    for (int j = 0; j < 16; ++j) {
        const int e = tid * 16 + j;
        const float z = 1.5f * Zf[e] - 0.5f * Sf[e];
        Zf[e] = z;
        wm[e] = z * wsq;
    }
    __syncthreads();

    // b = wm * mu
    if (tid < 64) {
        float acc = 0.f;
        #pragma unroll
        for (int j = 0; j < 64; ++j) {
            const int c = (j + tid) & 63;
            acc += Zf[tid * 64 + c] * mu[c];
        }
        bvec[tid] = acc * wsq;
    }
}

// ---------------------------------------------------------------------------
// K3: out[n][c][hw] = sum_c' wm[c][c'] * X[n][c'][hw] - b[c]
// R4 rewrite: R3's acc[64]/thread forced accumulators into AGPRs
// (VGPR_Count=36 + accvgpr_read/write per fma => 3x VALU, 70us). Now each
// wave owns 16 channels (acc[16] in VGPRs); X tile staged via LDS so the
// channel split costs no extra global traffic. wm symmetric => row cp gives
// column cp: 16 contiguous wave-uniform scalars per cp (s_load path via
// readfirstlane).
// ---------------------------------------------------------------------------
__global__ __launch_bounds__(256) void k3_whiten(const float* __restrict__ X,
                                                 const float* __restrict__ wm,
                                                 const float* __restrict__ bvec,
                                                 float* __restrict__ out) {
    __shared__ float xs[64 * 64];  // [cp][pos], 16 KB
    const int tid = threadIdx.x;
    const int l = tid & 63;
    // wave-uniform channel base (readfirstlane => scalar-load path for wm/bvec)
    const int wq = __builtin_amdgcn_readfirstlane(tid >> 6) * 16;

    const uint32_t g = blockIdx.x;           // 6272 posgroups, 49/image
    const uint32_t n = g / 49u;
    const uint32_t hw0 = (g - n * 49u) * 64u;
    const size_t base = (size_t)n * (CCH * HWSZ) + hw0;

    // stage 64ch x 64pos tile (coalesced float4; 2-way LDS aliasing is free)
    #pragma unroll
    for (int cb = 0; cb < 4; ++cb) {
        const int cp = cb * 16 + (tid >> 4);
        const int p4 = (tid & 15) * 4;
        *(f32x4*)&xs[cp * 64 + p4] =
            *(const f32x4*)(X + base + (size_t)cp * HWSZ + p4);
    }
    __syncthreads();

    float acc[16];
    #pragma unroll
    for (int j = 0; j < 16; ++j) acc[j] = 0.f;

    #pragma unroll 2
    for (int cp = 0; cp < 64; ++cp) {
        const float xv = xs[cp * 64 + l];
        const float* wr = wm + cp * 64 + wq;  // symmetric: wm[cp][wq+j] == wm[wq+j][cp]
        #pragma unroll
        for (int j = 0; j < 16; ++j) acc[j] = fmaf(wr[j], xv, acc[j]);
    }

    #pragma unroll
    for (int j = 0; j < 16; ++j)
        out[base + (size_t)(wq + j) * HWSZ + l] = acc[j] - bvec[wq + j];
}

// ---------------------------------------------------------------------------
extern "C" void kernel_launch(void* const* d_in, const int* in_sizes, int n_in,
                              void* d_out, int out_size, void* d_ws, size_t ws_size,
                              hipStream_t stream) {
    (void)in_sizes; (void)n_in; (void)out_size;
    const float* X = (const float*)d_in[0];
    float* out = (float*)d_out;
    float* ws = (float*)d_ws;

    // ws layout: [0..WS_TAIL) result area | nb K1 slots | RG stage-2 slots
    long avail = (long)(ws_size / sizeof(float)) - WS_TAIL - (long)RG * SLOT;
    int nb = (int)(avail / SLOT);
    if (nb > K1MAX) nb = K1MAX;
    if (nb < 1) nb = 1;

    float* part = ws + WS_TAIL;
    float* part2 = part + (size_t)nb * SLOT;

    k1_gram<<<nb, 256, 0, stream>>>(X, part, nb);
    k1b1_reduce<<<17 * RG, 256, 0, stream>>>(part, part2, nb);
    k1b2_reduce<<<17, 256, 0, stream>>>(part2, ws);
    k2_ns<<<1, 256, 0, stream>>>(ws);
    k3_whiten<<<MCOLS / 64, 256, 0, stream>>>(X, ws + 4160, ws + 8256, out);
}